// Round 2
// baseline (1416.280 us; speedup 1.0000x reference)
//
#include <hip/hip_runtime.h>
#include <hip/hip_bf16.h>
#include <math.h>

#define BATCH 4
#define SEQ 2048
#define DMODEL 1024
#define DATTN 1024

#define BM 128
#define BN 128
#define BKK 16

// ---------------------------------------------------------------------------
// Kernel 1: QKV projection GEMM.  C = X[8192,1024] @ W[1024,1024]
// grid = (M/128, N/128, 3), block = 256.  z selects {Wq,Wk,Wv} -> {Q,K,V}.
// ---------------------------------------------------------------------------
__global__ __launch_bounds__(256) void qkv_gemm(
    const float* __restrict__ X,
    const float* __restrict__ Wq,
    const float* __restrict__ Wk,
    const float* __restrict__ Wv,
    float* __restrict__ Q, float* __restrict__ K, float* __restrict__ V)
{
    const int zw = blockIdx.z;
    const float* __restrict__ W = (zw == 0) ? Wq : (zw == 1) ? Wk : Wv;
    float* __restrict__ C = (zw == 0) ? Q : (zw == 1) ? K : V;

    const int bm = blockIdx.x;      // 0..63
    const int bn = blockIdx.y;      // 0..7
    const int Kd = DMODEL, N = DATTN;

    __shared__ float As[BKK][BM];   // A^T tile
    __shared__ float Bs[BKK][BN];

    const int tid = threadIdx.x;
    const int tx = tid & 15, ty = tid >> 4;

    float acc[8][8];
    #pragma unroll
    for (int r = 0; r < 8; ++r)
        #pragma unroll
        for (int c = 0; c < 8; ++c) acc[r][c] = 0.f;

    const float* Xblk = X + (size_t)bm * BM * Kd;
    const float* Wblk = W + (size_t)bn * BN;

    for (int k0 = 0; k0 < Kd; k0 += BKK) {
        // A tile: 128 rows x 16 k, transpose into As[k][m]
        #pragma unroll
        for (int l = 0; l < 2; ++l) {
            int idx = tid + 256 * l;          // 0..511 float4s
            int row = idx >> 2, kq = idx & 3;
            float4 a = *(const float4*)(Xblk + (size_t)row * Kd + k0 + kq * 4);
            As[kq * 4 + 0][row] = a.x;
            As[kq * 4 + 1][row] = a.y;
            As[kq * 4 + 2][row] = a.z;
            As[kq * 4 + 3][row] = a.w;
        }
        // B tile: 16 k x 128 n, direct copy
        #pragma unroll
        for (int l = 0; l < 2; ++l) {
            int idx = tid + 256 * l;
            int krow = idx >> 5, nq = idx & 31;
            *(float4*)&Bs[krow][nq * 4] =
                *(const float4*)(Wblk + (size_t)(k0 + krow) * N + nq * 4);
        }
        __syncthreads();
        #pragma unroll
        for (int k = 0; k < BKK; ++k) {
            float4 a0 = *(float4*)&As[k][ty * 8];
            float4 a1 = *(float4*)&As[k][ty * 8 + 4];
            float4 b0 = *(float4*)&Bs[k][tx * 8];
            float4 b1 = *(float4*)&Bs[k][tx * 8 + 4];
            float av[8] = {a0.x, a0.y, a0.z, a0.w, a1.x, a1.y, a1.z, a1.w};
            float bv[8] = {b0.x, b0.y, b0.z, b0.w, b1.x, b1.y, b1.z, b1.w};
            #pragma unroll
            for (int r = 0; r < 8; ++r)
                #pragma unroll
                for (int c = 0; c < 8; ++c)
                    acc[r][c] = fmaf(av[r], bv[c], acc[r][c]);
        }
        __syncthreads();
    }

    float* Cblk = C + (size_t)(bm * BM) * N + (size_t)bn * BN;
    #pragma unroll
    for (int r = 0; r < 8; ++r) {
        float4 v0 = {acc[r][0], acc[r][1], acc[r][2], acc[r][3]};
        float4 v1 = {acc[r][4], acc[r][5], acc[r][6], acc[r][7]};
        *(float4*)(Cblk + (size_t)(ty * 8 + r) * N + tx * 8)     = v0;
        *(float4*)(Cblk + (size_t)(ty * 8 + r) * N + tx * 8 + 4) = v1;
    }
}

// ---------------------------------------------------------------------------
// Kernel 2: masked scaled scores.  P[b,i,j] = (Q_i . K_j)/32 for j<=i+1 else -inf
// grid = (16 jt, 16 t, 4 b), block 256.  Only jt <= t+1 computed.
// ---------------------------------------------------------------------------
__global__ __launch_bounds__(256) void scores_kernel(
    const float* __restrict__ Q, const float* __restrict__ K,
    float* __restrict__ P)
{
    const int jt = blockIdx.x;
    const int t  = blockIdx.y;
    const int b  = blockIdx.z;
    if (jt > t + 1) return;

    const int S = SEQ, Da = DATTN;
    const float* Qb = Q + ((size_t)b * S + (size_t)t * BM) * Da;
    const float* Kb = K + ((size_t)b * S + (size_t)jt * BN) * Da;
    float* Pb = P + (size_t)b * S * S + (size_t)t * BM * S + (size_t)jt * BN;

    __shared__ float As[BKK][BM];
    __shared__ float Bs[BKK][BN];

    const int tid = threadIdx.x;
    const int tx = tid & 15, ty = tid >> 4;

    float acc[8][8];
    #pragma unroll
    for (int r = 0; r < 8; ++r)
        #pragma unroll
        for (int c = 0; c < 8; ++c) acc[r][c] = 0.f;

    for (int k0 = 0; k0 < Da; k0 += BKK) {
        #pragma unroll
        for (int l = 0; l < 2; ++l) {
            int idx = tid + 256 * l;
            int row = idx >> 2, kq = idx & 3;
            float4 a = *(const float4*)(Qb + (size_t)row * Da + k0 + kq * 4);
            As[kq * 4 + 0][row] = a.x;
            As[kq * 4 + 1][row] = a.y;
            As[kq * 4 + 2][row] = a.z;
            As[kq * 4 + 3][row] = a.w;
        }
        #pragma unroll
        for (int l = 0; l < 2; ++l) {
            int idx = tid + 256 * l;
            int row = idx >> 2, kq = idx & 3;
            float4 a = *(const float4*)(Kb + (size_t)row * Da + k0 + kq * 4);
            Bs[kq * 4 + 0][row] = a.x;
            Bs[kq * 4 + 1][row] = a.y;
            Bs[kq * 4 + 2][row] = a.z;
            Bs[kq * 4 + 3][row] = a.w;
        }
        __syncthreads();
        #pragma unroll
        for (int k = 0; k < BKK; ++k) {
            float4 a0 = *(float4*)&As[k][ty * 8];
            float4 a1 = *(float4*)&As[k][ty * 8 + 4];
            float4 b0 = *(float4*)&Bs[k][tx * 8];
            float4 b1 = *(float4*)&Bs[k][tx * 8 + 4];
            float av[8] = {a0.x, a0.y, a0.z, a0.w, a1.x, a1.y, a1.z, a1.w};
            float bv[8] = {b0.x, b0.y, b0.z, b0.w, b1.x, b1.y, b1.z, b1.w};
            #pragma unroll
            for (int r = 0; r < 8; ++r)
                #pragma unroll
                for (int c = 0; c < 8; ++c)
                    acc[r][c] = fmaf(av[r], bv[c], acc[r][c]);
        }
        __syncthreads();
    }

    const float scale = 1.0f / 32.0f;   // 1/sqrt(1024)
    #pragma unroll
    for (int r = 0; r < 8; ++r) {
        int i = t * BM + ty * 8 + r;
        #pragma unroll
        for (int c = 0; c < 8; ++c) {
            int j = jt * BN + tx * 8 + c;
            float v = (j <= i + 1) ? acc[r][c] * scale : -INFINITY;
            Pb[(size_t)(ty * 8 + r) * S + tx * 8 + c] = v;
        }
    }
}

// ---------------------------------------------------------------------------
// Kernel 3: row softmax over the written causal range.
// grid = 8192 rows, block 256.
// ---------------------------------------------------------------------------
__global__ __launch_bounds__(256) void softmax_kernel(float* __restrict__ P)
{
    const int row = blockIdx.x;
    const int b = row >> 11, i = row & (SEQ - 1);
    const int t = i >> 7;
    const int L = min(SEQ, (t + 2) * BM);
    float* p = P + ((size_t)b * SEQ + i) * SEQ;
    const int tid = threadIdx.x;

    __shared__ float red[4];

    float m = -INFINITY;
    for (int j = tid; j < L; j += 256) m = fmaxf(m, p[j]);
    #pragma unroll
    for (int o = 32; o > 0; o >>= 1) m = fmaxf(m, __shfl_xor(m, o));
    if ((tid & 63) == 0) red[tid >> 6] = m;
    __syncthreads();
    m = fmaxf(fmaxf(red[0], red[1]), fmaxf(red[2], red[3]));
    __syncthreads();

    float s = 0.f;
    for (int j = tid; j < L; j += 256) {
        float e = __expf(p[j] - m);
        p[j] = e;
        s += e;
    }
    #pragma unroll
    for (int o = 32; o > 0; o >>= 1) s += __shfl_xor(s, o);
    if ((tid & 63) == 0) red[tid >> 6] = s;
    __syncthreads();
    s = red[0] + red[1] + red[2] + red[3];
    const float inv = 1.f / s;
    for (int j = tid; j < L; j += 256) p[j] *= inv;
}

// ---------------------------------------------------------------------------
// Kernel 4: Out = P @ V over the valid causal j range.
// grid = (8 n-tiles, 16 t, 4 b), block 256.
// ---------------------------------------------------------------------------
__global__ __launch_bounds__(256) void pv_gemm(
    const float* __restrict__ P, const float* __restrict__ V,
    float* __restrict__ Out)
{
    const int bn = blockIdx.x;  // 0..7
    const int t  = blockIdx.y;  // 0..15
    const int b  = blockIdx.z;
    const int S = SEQ, N = DATTN;
    const int jlim = min(S, (t + 2) * BM);

    const float* Pb = P + (size_t)b * S * S + (size_t)t * BM * S;
    const float* Vb = V + (size_t)b * S * N + (size_t)bn * BN;

    __shared__ float As[BKK][BM];
    __shared__ float Bs[BKK][BN];

    const int tid = threadIdx.x;
    const int tx = tid & 15, ty = tid >> 4;

    float acc[8][8];
    #pragma unroll
    for (int r = 0; r < 8; ++r)
        #pragma unroll
        for (int c = 0; c < 8; ++c) acc[r][c] = 0.f;

    for (int k0 = 0; k0 < jlim; k0 += BKK) {
        #pragma unroll
        for (int l = 0; l < 2; ++l) {
            int idx = tid + 256 * l;
            int row = idx >> 2, kq = idx & 3;
            float4 a = *(const float4*)(Pb + (size_t)row * S + k0 + kq * 4);
            As[kq * 4 + 0][row] = a.x;
            As[kq * 4 + 1][row] = a.y;
            As[kq * 4 + 2][row] = a.z;
            As[kq * 4 + 3][row] = a.w;
        }
        #pragma unroll
        for (int l = 0; l < 2; ++l) {
            int idx = tid + 256 * l;
            int krow = idx >> 5, nq = idx & 31;
            *(float4*)&Bs[krow][nq * 4] =
                *(const float4*)(Vb + (size_t)(k0 + krow) * N + nq * 4);
        }
        __syncthreads();
        #pragma unroll
        for (int k = 0; k < BKK; ++k) {
            float4 a0 = *(float4*)&As[k][ty * 8];
            float4 a1 = *(float4*)&As[k][ty * 8 + 4];
            float4 b0 = *(float4*)&Bs[k][tx * 8];
            float4 b1 = *(float4*)&Bs[k][tx * 8 + 4];
            float av[8] = {a0.x, a0.y, a0.z, a0.w, a1.x, a1.y, a1.z, a1.w};
            float bv[8] = {b0.x, b0.y, b0.z, b0.w, b1.x, b1.y, b1.z, b1.w};
            #pragma unroll
            for (int r = 0; r < 8; ++r)
                #pragma unroll
                for (int c = 0; c < 8; ++c)
                    acc[r][c] = fmaf(av[r], bv[c], acc[r][c]);
        }
        __syncthreads();
    }

    float* Ob = Out + ((size_t)b * S + (size_t)t * BM) * N + (size_t)bn * BN;
    #pragma unroll
    for (int r = 0; r < 8; ++r) {
        float4 v0 = {acc[r][0], acc[r][1], acc[r][2], acc[r][3]};
        float4 v1 = {acc[r][4], acc[r][5], acc[r][6], acc[r][7]};
        *(float4*)(Ob + (size_t)(ty * 8 + r) * N + tx * 8)     = v0;
        *(float4*)(Ob + (size_t)(ty * 8 + r) * N + tx * 8 + 4) = v1;
    }
}

// ---------------------------------------------------------------------------
extern "C" void kernel_launch(void* const* d_in, const int* in_sizes, int n_in,
                              void* d_out, int out_size, void* d_ws, size_t ws_size,
                              hipStream_t stream)
{
    const float* x  = (const float*)d_in[0];
    const float* Wq = (const float*)d_in[1];
    const float* Wk = (const float*)d_in[2];
    const float* Wv = (const float*)d_in[3];

    float* Q = (float*)d_out;                       // reuse output as Q scratch
    float* K = (float*)d_ws;                        // 8M floats
    float* V = K + (size_t)BATCH * SEQ * DATTN;     // 8M floats
    float* P = V + (size_t)BATCH * SEQ * DATTN;     // 16M floats (scores)

    // 1) Q,K,V projections
    {
        dim3 grid(BATCH * SEQ / BM, DATTN / BN, 3);
        qkv_gemm<<<grid, 256, 0, stream>>>(x, Wq, Wk, Wv, Q, K, V);
    }
    // 2) masked scaled scores
    {
        dim3 grid(SEQ / BN, SEQ / BM, BATCH);
        scores_kernel<<<grid, 256, 0, stream>>>(Q, K, P);
    }
    // 3) softmax
    {
        dim3 grid(BATCH * SEQ);
        softmax_kernel<<<grid, 256, 0, stream>>>(P);
    }
    // 4) Out = P @ V
    {
        dim3 grid(DATTN / BN, SEQ / BM, BATCH);
        pv_gemm<<<grid, 256, 0, stream>>>(P, V, (float*)d_out);
    }
}

// Round 7
// 373.561 us; speedup vs baseline: 3.7913x; 3.7913x over previous
//
#include <hip/hip_runtime.h>
#include <math.h>

#define BATCH 4
#define SEQ 2048
#define DM 1024
#define NTOK (BATCH * SEQ)                 // 8192
#define NE ((size_t)NTOK * DM)             // 8,388,608 elements
#define WN ((size_t)DM * DM)               // 1,048,576 elements

using s16x8 = __attribute__((ext_vector_type(8))) short;
using f32x4 = __attribute__((ext_vector_type(4))) float;

// ---- bf16 helpers (RNE) ----------------------------------------------------
__device__ __forceinline__ unsigned short f2bf(float f) {
    unsigned u = __builtin_bit_cast(unsigned, f);
    u += 0x7FFFu + ((u >> 16) & 1u);
    return (unsigned short)(u >> 16);
}
__device__ __forceinline__ float bf2f(unsigned short h) {
    unsigned u = ((unsigned)h) << 16;
    return __builtin_bit_cast(float, u);
}

__device__ __forceinline__ f32x4 MFMA(s16x8 a, s16x8 b, f32x4 c) {
    return __builtin_amdgcn_mfma_f32_16x16x32_bf16(a, b, c, 0, 0, 0);
}

#define AS1 __attribute__((address_space(1)))
#define AS3 __attribute__((address_space(3)))
__device__ __forceinline__ void gll16(const void* g, void* l) {
    __builtin_amdgcn_global_load_lds((const AS1 void*)g, (AS3 void*)l, 16, 0, 0);
}

// LDS tile layout: [128 rows][64 bf16], 8 granules(16B) per row,
// granule g of row r stored at position (g ^ (r&7))  -> bank-conflict-free reads.
__device__ __forceinline__ s16x8 lds_frag(const short* base, int row, int g) {
    return *(const s16x8*)(base + row * 64 + ((g ^ (row & 7)) << 3));
}

// Stage a [128][64] bf16 tile from global (row stride rs elements) into LDS,
// swizzle applied by permuting the per-lane GLOBAL source (linear LDS dest).
__device__ __forceinline__ void stage_tile(const unsigned short* g0, size_t rs,
                                           short* lds, int tid) {
    int lane = tid & 63, w = tid >> 6;
    #pragma unroll
    for (int c = 0; c < 4; ++c) {
        int s = c * 256 + w * 64 + lane;     // 16B slot id; dest = base + lane*16
        int row = s >> 3, gg = s & 7;
        int graw = gg ^ (row & 7);
        gll16(g0 + (size_t)row * rs + graw * 8, lds + (size_t)s * 8);
    }
}

// ---------------------------------------------------------------------------
// split_x: x fp32 -> x_hi, x_lo bf16 (same layout)
// ---------------------------------------------------------------------------
__global__ __launch_bounds__(256) void split_x(const float* __restrict__ x,
                                               unsigned short* __restrict__ xh,
                                               unsigned short* __restrict__ xl) {
    size_t n4 = NE / 4;
    for (size_t i = (size_t)blockIdx.x * 256 + threadIdx.x; i < n4;
         i += (size_t)gridDim.x * 256) {
        float4 v = ((const float4*)x)[i];
        ushort4 h, l;
        h.x = f2bf(v.x); l.x = f2bf(v.x - bf2f(h.x));
        h.y = f2bf(v.y); l.y = f2bf(v.y - bf2f(h.y));
        h.z = f2bf(v.z); l.z = f2bf(v.z - bf2f(h.z));
        h.w = f2bf(v.w); l.w = f2bf(v.w - bf2f(h.w));
        ((ushort4*)xh)[i] = h;
        ((ushort4*)xl)[i] = l;
    }
}

// ---------------------------------------------------------------------------
// split_wt: W [d][n] fp32 -> Wt_hi/lo [n][d] bf16 (transposed), z selects Wq/Wk/Wv
// ---------------------------------------------------------------------------
__global__ __launch_bounds__(256) void split_wt(const float* __restrict__ Wq,
                                                const float* __restrict__ Wk,
                                                const float* __restrict__ Wv,
                                                unsigned short* __restrict__ Wsp) {
    const int z = blockIdx.z;
    const float* W = (z == 0) ? Wq : (z == 1) ? Wk : Wv;
    unsigned short* oh = Wsp + (size_t)z * 2 * WN;
    unsigned short* ol = oh + WN;

    __shared__ float t[64][65];
    const int d0 = blockIdx.x * 64, n0 = blockIdx.y * 64;
    const int tid = threadIdx.x;
    #pragma unroll
    for (int c = 0; c < 16; ++c) {
        int f = c * 256 + tid; int r = f >> 6, cc = f & 63;
        t[r][cc] = W[(size_t)(d0 + r) * DM + n0 + cc];
    }
    __syncthreads();
    #pragma unroll
    for (int c = 0; c < 16; ++c) {
        int f = c * 256 + tid; int r = f >> 6, cc = f & 63;
        float v = t[cc][r];                       // Wt[n0+r][d0+cc] = W[d0+cc][n0+r]
        unsigned short h = f2bf(v);
        size_t o = (size_t)(n0 + r) * DM + d0 + cc;
        oh[o] = h;
        ol[o] = f2bf(v - bf2f(h));
    }
}

// ---------------------------------------------------------------------------
// qk_mfma: C = x @ W (3-term split), writes C split into hi/lo bf16.
// grid (64, 8, 2): z=0 -> Q (into d_out), z=1 -> K.
// ---------------------------------------------------------------------------
__global__ __launch_bounds__(256, 2) void qk_mfma(
    const unsigned short* __restrict__ xh, const unsigned short* __restrict__ xl,
    const unsigned short* __restrict__ Wsp,
    unsigned short* __restrict__ Qh, unsigned short* __restrict__ Ql,
    unsigned short* __restrict__ Kh, unsigned short* __restrict__ Kl) {
    const int z = blockIdx.z;
    const unsigned short* Wh = Wsp + (size_t)z * 2 * WN;
    const unsigned short* Wl = Wh + WN;
    unsigned short* Ch = z ? Kh : Qh;
    unsigned short* Cl = z ? Kl : Ql;

    const int m0 = blockIdx.x * 128, n0 = blockIdx.y * 128;
    __shared__ short Ah[128 * 64], Al[128 * 64], Bh[128 * 64], Bl[128 * 64];
    const int tid = threadIdx.x, lane = tid & 63, w = tid >> 6;
    const int wr = w >> 1, wc = w & 1;

    f32x4 acc[4][4];
    #pragma unroll
    for (int i = 0; i < 4; ++i)
        #pragma unroll
        for (int j = 0; j < 4; ++j) acc[i][j] = (f32x4){0.f, 0.f, 0.f, 0.f};

    for (int k0 = 0; k0 < DM; k0 += 64) {
        stage_tile(xh + (size_t)m0 * DM + k0, DM, Ah, tid);
        stage_tile(xl + (size_t)m0 * DM + k0, DM, Al, tid);
        stage_tile(Wh + (size_t)n0 * DM + k0, DM, Bh, tid);
        stage_tile(Wl + (size_t)n0 * DM + k0, DM, Bl, tid);
        __syncthreads();
        #pragma unroll
        for (int ks = 0; ks < 2; ++ks) {
            const int g = ks * 4 + (lane >> 4);
            s16x8 a_h[4], a_l[4], b_h[4], b_l[4];
            #pragma unroll
            for (int mi = 0; mi < 4; ++mi) {
                int r = wr * 64 + mi * 16 + (lane & 15);
                a_h[mi] = lds_frag(Ah, r, g);
                a_l[mi] = lds_frag(Al, r, g);
            }
            #pragma unroll
            for (int ni = 0; ni < 4; ++ni) {
                int r = wc * 64 + ni * 16 + (lane & 15);
                b_h[ni] = lds_frag(Bh, r, g);
                b_l[ni] = lds_frag(Bl, r, g);
            }
            #pragma unroll
            for (int mi = 0; mi < 4; ++mi)
                #pragma unroll
                for (int ni = 0; ni < 4; ++ni) {
                    acc[mi][ni] = MFMA(a_h[mi], b_h[ni], acc[mi][ni]);
                    acc[mi][ni] = MFMA(a_h[mi], b_l[ni], acc[mi][ni]);
                    acc[mi][ni] = MFMA(a_l[mi], b_h[ni], acc[mi][ni]);
                }
        }
        __syncthreads();
    }
    // epilogue: split C into hi/lo bf16.  D: col=lane&15, row=(lane>>4)*4+r
    #pragma unroll
    for (int mi = 0; mi < 4; ++mi)
        #pragma unroll
        for (int ni = 0; ni < 4; ++ni)
            #pragma unroll
            for (int r = 0; r < 4; ++r) {
                int row = m0 + wr * 64 + mi * 16 + (lane >> 4) * 4 + r;
                int col = n0 + wc * 64 + ni * 16 + (lane & 15);
                float v = acc[mi][ni][r];
                unsigned short h = f2bf(v);
                size_t o = (size_t)row * DM + col;
                Ch[o] = h;
                Cl[o] = f2bf(v - bf2f(h));
            }
}

// ---------------------------------------------------------------------------
// vt_mfma: Vt[n][m] = (x @ Wv)^T via GEMM A=Wt_v(hi), B=x(hi), 1-term.
// grid (8 n-tiles over 1024, 64 m-tiles over 8192)
// ---------------------------------------------------------------------------
__global__ __launch_bounds__(256, 2) void vt_mfma(
    const unsigned short* __restrict__ Wsp, const unsigned short* __restrict__ xh,
    unsigned short* __restrict__ Vt) {
    const unsigned short* Wvh = Wsp + 4 * WN;   // Wv hi
    const int m0 = blockIdx.x * 128;            // over n-dim (1024)
    const int n0 = blockIdx.y * 128;            // over seq (8192)
    __shared__ short Ah[128 * 64], Bh[128 * 64];
    const int tid = threadIdx.x, lane = tid & 63, w = tid >> 6;
    const int wr = w >> 1, wc = w & 1;

    f32x4 acc[4][4];
    #pragma unroll
    for (int i = 0; i < 4; ++i)
        #pragma unroll
        for (int j = 0; j < 4; ++j) acc[i][j] = (f32x4){0.f, 0.f, 0.f, 0.f};

    for (int k0 = 0; k0 < DM; k0 += 64) {
        stage_tile(Wvh + (size_t)m0 * DM + k0, DM, Ah, tid);
        stage_tile(xh + (size_t)n0 * DM + k0, DM, Bh, tid);
        __syncthreads();
        #pragma unroll
        for (int ks = 0; ks < 2; ++ks) {
            const int g = ks * 4 + (lane >> 4);
            s16x8 a_h[4], b_h[4];
            #pragma unroll
            for (int mi = 0; mi < 4; ++mi)
                a_h[mi] = lds_frag(Ah, wr * 64 + mi * 16 + (lane & 15), g);
            #pragma unroll
            for (int ni = 0; ni < 4; ++ni)
                b_h[ni] = lds_frag(Bh, wc * 64 + ni * 16 + (lane & 15), g);
            #pragma unroll
            for (int mi = 0; mi < 4; ++mi)
                #pragma unroll
                for (int ni = 0; ni < 4; ++ni)
                    acc[mi][ni] = MFMA(a_h[mi], b_h[ni], acc[mi][ni]);
        }
        __syncthreads();
    }
    #pragma unroll
    for (int mi = 0; mi < 4; ++mi)
        #pragma unroll
        for (int ni = 0; ni < 4; ++ni)
            #pragma unroll
            for (int r = 0; r < 4; ++r) {
                int row = m0 + wr * 64 + mi * 16 + (lane >> 4) * 4 + r;
                int col = n0 + wc * 64 + ni * 16 + (lane & 15);
                Vt[(size_t)row * NTOK + col] = f2bf(acc[mi][ni][r]);
            }
}

// ---------------------------------------------------------------------------
// scores_mfma: P = mask(Q.K^T)/32, fp32 out.  3-term split.
// grid (16 jt, 16 t, 4 b), early-exit jt > t+1.
// ---------------------------------------------------------------------------
__global__ __launch_bounds__(256, 2) void scores_mfma(
    const unsigned short* __restrict__ Qh, const unsigned short* __restrict__ Ql,
    const unsigned short* __restrict__ Kh, const unsigned short* __restrict__ Kl,
    float* __restrict__ P) {
    const int jt = blockIdx.x, t = blockIdx.y, b = blockIdx.z;
    if (jt > t + 1) return;
    const int m0 = t * 128, n0 = jt * 128;
    const size_t qrow0 = (size_t)b * SEQ + m0;
    const size_t krow0 = (size_t)b * SEQ + n0;

    __shared__ short Ah[128 * 64], Al[128 * 64], Bh[128 * 64], Bl[128 * 64];
    const int tid = threadIdx.x, lane = tid & 63, w = tid >> 6;
    const int wr = w >> 1, wc = w & 1;

    f32x4 acc[4][4];
    #pragma unroll
    for (int i = 0; i < 4; ++i)
        #pragma unroll
        for (int j = 0; j < 4; ++j) acc[i][j] = (f32x4){0.f, 0.f, 0.f, 0.f};

    for (int k0 = 0; k0 < DM; k0 += 64) {
        stage_tile(Qh + qrow0 * DM + k0, DM, Ah, tid);
        stage_tile(Ql + qrow0 * DM + k0, DM, Al, tid);
        stage_tile(Kh + krow0 * DM + k0, DM, Bh, tid);
        stage_tile(Kl + krow0 * DM + k0, DM, Bl, tid);
        __syncthreads();
        #pragma unroll
        for (int ks = 0; ks < 2; ++ks) {
            const int g = ks * 4 + (lane >> 4);
            s16x8 a_h[4], a_l[4], b_h[4], b_l[4];
            #pragma unroll
            for (int mi = 0; mi < 4; ++mi) {
                int r = wr * 64 + mi * 16 + (lane & 15);
                a_h[mi] = lds_frag(Ah, r, g);
                a_l[mi] = lds_frag(Al, r, g);
            }
            #pragma unroll
            for (int ni = 0; ni < 4; ++ni) {
                int r = wc * 64 + ni * 16 + (lane & 15);
                b_h[ni] = lds_frag(Bh, r, g);
                b_l[ni] = lds_frag(Bl, r, g);
            }
            #pragma unroll
            for (int mi = 0; mi < 4; ++mi)
                #pragma unroll
                for (int ni = 0; ni < 4; ++ni) {
                    acc[mi][ni] = MFMA(a_h[mi], b_h[ni], acc[mi][ni]);
                    acc[mi][ni] = MFMA(a_h[mi], b_l[ni], acc[mi][ni]);
                    acc[mi][ni] = MFMA(a_l[mi], b_h[ni], acc[mi][ni]);
                }
        }
        __syncthreads();
    }
    const float scale = 1.0f / 32.0f;
    #pragma unroll
    for (int mi = 0; mi < 4; ++mi)
        #pragma unroll
        for (int ni = 0; ni < 4; ++ni)
            #pragma unroll
            for (int r = 0; r < 4; ++r) {
                int i = m0 + wr * 64 + mi * 16 + (lane >> 4) * 4 + r;  // within batch
                int j = n0 + wc * 64 + ni * 16 + (lane & 15);
                float v = (j <= i + 1) ? acc[mi][ni][r] * scale : -INFINITY;
                P[((size_t)b * SEQ + i) * SEQ + j] = v;
            }
}

// ---------------------------------------------------------------------------
// softmax over the causal range [0, L) of each row (in-place fp32).
// ---------------------------------------------------------------------------
__global__ __launch_bounds__(256) void softmax_kernel(float* __restrict__ P) {
    const int row = blockIdx.x;
    const int b = row >> 11, i = row & (SEQ - 1);
    const int t = i >> 7;
    const int L = min(SEQ, (t + 2) * 128);
    float* p = P + ((size_t)b * SEQ + i) * SEQ;
    const int tid = threadIdx.x;
    __shared__ float red[4];

    float m = -INFINITY;
    for (int j = tid; j < L; j += 256) m = fmaxf(m, p[j]);
    #pragma unroll
    for (int o = 32; o > 0; o >>= 1) m = fmaxf(m, __shfl_xor(m, o));
    if ((tid & 63) == 0) red[tid >> 6] = m;
    __syncthreads();
    m = fmaxf(fmaxf(red[0], red[1]), fmaxf(red[2], red[3]));
    __syncthreads();

    float s = 0.f;
    for (int j = tid; j < L; j += 256) {
        float e = __expf(p[j] - m);
        p[j] = e;
        s += e;
    }
    #pragma unroll
    for (int o = 32; o > 0; o >>= 1) s += __shfl_xor(s, o);
    if ((tid & 63) == 0) red[tid >> 6] = s;
    __syncthreads();
    s = red[0] + red[1] + red[2] + red[3];
    const float inv = 1.f / s;
    for (int j = tid; j < L; j += 256) p[j] *= inv;
}

// ---------------------------------------------------------------------------
// pv_mfma: Out = P @ V, 1-term bf16.  A = P (fp32 reg-staged -> bf16), B = Vt.
// grid (8 n-tiles, 16 t, 4 b)
// ---------------------------------------------------------------------------
__global__ __launch_bounds__(256, 2) void pv_mfma(
    const float* __restrict__ P, const unsigned short* __restrict__ Vt,
    float* __restrict__ Out) {
    const int bx = blockIdx.x, t = blockIdx.y, b = blockIdx.z;
    const int m0 = t * 128, n0 = bx * 128;
    const int jlim = min(SEQ, (t + 2) * 128);

    __shared__ short Pa[128 * 64], Vb[128 * 64];
    const int tid = threadIdx.x, lane = tid & 63, w = tid >> 6;
    const int wr = w >> 1, wc = w & 1;

    f32x4 acc[4][4];
    #pragma unroll
    for (int i = 0; i < 4; ++i)
        #pragma unroll
        for (int j = 0; j < 4; ++j) acc[i][j] = (f32x4){0.f, 0.f, 0.f, 0.f};

    for (int k0 = 0; k0 < jlim; k0 += 64) {
        // A tile: convert P fp32 -> bf16, swizzled ds_write (reg-staged).
        #pragma unroll
        for (int c = 0; c < 4; ++c) {
            int s = c * 256 + tid;
            int row = s >> 3, gg = s & 7, graw = gg ^ (row & 7);
            const float* src = P + ((size_t)b * SEQ + m0 + row) * SEQ + k0 + graw * 8;
            float4 v0 = ((const float4*)src)[0];
            float4 v1 = ((const float4*)src)[1];
            s16x8 pk;
            pk[0] = (short)f2bf(v0.x); pk[1] = (short)f2bf(v0.y);
            pk[2] = (short)f2bf(v0.z); pk[3] = (short)f2bf(v0.w);
            pk[4] = (short)f2bf(v1.x); pk[5] = (short)f2bf(v1.y);
            pk[6] = (short)f2bf(v1.z); pk[7] = (short)f2bf(v1.w);
            *(s16x8*)(Pa + (size_t)s * 8) = pk;
        }
        // B tile: Vt rows = out-cols n, k = seq j (per batch offset)
        stage_tile(Vt + (size_t)n0 * NTOK + (size_t)b * SEQ + k0, NTOK, Vb, tid);
        __syncthreads();
        #pragma unroll
        for (int ks = 0; ks < 2; ++ks) {
            const int g = ks * 4 + (lane >> 4);
            s16x8 a_h[4], b_h[4];
            #pragma unroll
            for (int mi = 0; mi < 4; ++mi)
                a_h[mi] = lds_frag(Pa, wr * 64 + mi * 16 + (lane & 15), g);
            #pragma unroll
            for (int ni = 0; ni < 4; ++ni)
                b_h[ni] = lds_frag(Vb, wc * 64 + ni * 16 + (lane & 15), g);
            #pragma unroll
            for (int mi = 0; mi < 4; ++mi)
                #pragma unroll
                for (int ni = 0; ni < 4; ++ni)
                    acc[mi][ni] = MFMA(a_h[mi], b_h[ni], acc[mi][ni]);
        }
        __syncthreads();
    }
    #pragma unroll
    for (int mi = 0; mi < 4; ++mi)
        #pragma unroll
        for (int ni = 0; ni < 4; ++ni)
            #pragma unroll
            for (int r = 0; r < 4; ++r) {
                int i = m0 + wr * 64 + mi * 16 + (lane >> 4) * 4 + r;
                int col = n0 + wc * 64 + ni * 16 + (lane & 15);
                Out[((size_t)b * SEQ + i) * DM + col] = acc[mi][ni][r];
            }
}

// ---------------------------------------------------------------------------
extern "C" void kernel_launch(void* const* d_in, const int* in_sizes, int n_in,
                              void* d_out, int out_size, void* d_ws, size_t ws_size,
                              hipStream_t stream) {
    const float* x  = (const float*)d_in[0];
    const float* Wq = (const float*)d_in[1];
    const float* Wk = (const float*)d_in[2];
    const float* Wv = (const float*)d_in[3];

    // Workspace layout (bytes, NE = 8.39M elems):
    //   [0        , 2*NE)  : K_hi, K_lo           (bf16)       -- live till scores
    //   [2*NE*2B..] actually element-wise below:
    char* ws = (char*)d_ws;
    unsigned short* Kh = (unsigned short*)ws;            // NE
    unsigned short* Kl = Kh + NE;                        // NE
    unsigned short* Vt = Kl + NE;                        // NE   [n=1024][m=8192]
    float* P = (float*)(ws + 6 * NE);                    // 4*S*S fp32 = 8*NE bytes
    // x / W splits live INSIDE P's byte range (dead before scores writes P):
    unsigned short* xh  = (unsigned short*)(ws + 6 * NE);   // NE
    unsigned short* xl  = xh + NE;                          // NE
    unsigned short* Wsp = (unsigned short*)(ws + 10 * NE);  // 6*WN = 1.5*NE
    // Q splits use d_out as scratch (dead after scores; overwritten by Out):
    unsigned short* Qh = (unsigned short*)d_out;
    unsigned short* Ql = Qh + NE;

    split_x<<<2048, 256, 0, stream>>>(x, xh, xl);
    {
        dim3 g(16, 16, 3);
        split_wt<<<g, 256, 0, stream>>>(Wq, Wk, Wv, Wsp);
    }
    {
        dim3 g(NTOK / 128, DM / 128, 2);
        qk_mfma<<<g, 256, 0, stream>>>(xh, xl, Wsp, Qh, Ql, Kh, Kl);
    }
    {
        dim3 g(DM / 128, NTOK / 128, 1);
        vt_mfma<<<g, 256, 0, stream>>>(Wsp, xh, Vt);
    }
    {
        dim3 g(16, 16, 4);
        scores_mfma<<<g, 256, 0, stream>>>(Qh, Ql, Kh, Kl, P);
    }
    softmax_kernel<<<BATCH * SEQ, 256, 0, stream>>>(P);
    {
        dim3 g(DM / 128, 16, 4);
        pv_mfma<<<g, 256, 0, stream>>>(P, Vt, (float*)d_out);
    }
}

// Round 8
// 323.974 us; speedup vs baseline: 4.3716x; 1.1531x over previous
//
#include <hip/hip_runtime.h>
#include <math.h>

#define BATCH 4
#define SEQ 2048
#define DM 1024
#define NTOK (BATCH * SEQ)                 // 8192
#define NE ((size_t)NTOK * DM)             // 8,388,608 elements
#define WN ((size_t)DM * DM)               // 1,048,576 elements

using s16x8 = __attribute__((ext_vector_type(8))) short;
using f32x4 = __attribute__((ext_vector_type(4))) float;

// ---- bf16 helpers (RNE) ----------------------------------------------------
__device__ __forceinline__ unsigned short f2bf(float f) {
    unsigned u = __builtin_bit_cast(unsigned, f);
    u += 0x7FFFu + ((u >> 16) & 1u);
    return (unsigned short)(u >> 16);
}
__device__ __forceinline__ float bf2f(unsigned short h) {
    unsigned u = ((unsigned)h) << 16;
    return __builtin_bit_cast(float, u);
}

__device__ __forceinline__ f32x4 MFMA(s16x8 a, s16x8 b, f32x4 c) {
    return __builtin_amdgcn_mfma_f32_16x16x32_bf16(a, b, c, 0, 0, 0);
}

#define AS1 __attribute__((address_space(1)))
#define AS3 __attribute__((address_space(3)))
__device__ __forceinline__ void gll16(const void* g, void* l) {
    __builtin_amdgcn_global_load_lds((const AS1 void*)g, (AS3 void*)l, 16, 0, 0);
}

// LDS tile layout: [128 rows][64 bf16], 8 granules(16B) per row,
// granule g of row r stored at position (g ^ (r&7))  -> bank-conflict-free reads.
__device__ __forceinline__ s16x8 lds_frag(const short* base, int row, int g) {
    return *(const s16x8*)(base + row * 64 + ((g ^ (row & 7)) << 3));
}

// Stage a [128][64] bf16 tile from global (row stride rs elements) into LDS,
// swizzle applied by permuting the per-lane GLOBAL source (linear LDS dest).
__device__ __forceinline__ void stage_tile(const unsigned short* g0, size_t rs,
                                           short* lds, int tid) {
    int lane = tid & 63, w = tid >> 6;
    #pragma unroll
    for (int c = 0; c < 4; ++c) {
        int s = c * 256 + w * 64 + lane;     // 16B slot id; dest = base + lane*16
        int row = s >> 3, gg = s & 7;
        int graw = gg ^ (row & 7);
        gll16(g0 + (size_t)row * rs + graw * 8, lds + (size_t)s * 8);
    }
}

// ---------------------------------------------------------------------------
// split_x: x fp32 -> x_hi, x_lo bf16 (same layout)
// ---------------------------------------------------------------------------
__global__ __launch_bounds__(256) void split_x(const float* __restrict__ x,
                                               unsigned short* __restrict__ xh,
                                               unsigned short* __restrict__ xl) {
    size_t n4 = NE / 4;
    for (size_t i = (size_t)blockIdx.x * 256 + threadIdx.x; i < n4;
         i += (size_t)gridDim.x * 256) {
        float4 v = ((const float4*)x)[i];
        ushort4 h, l;
        h.x = f2bf(v.x); l.x = f2bf(v.x - bf2f(h.x));
        h.y = f2bf(v.y); l.y = f2bf(v.y - bf2f(h.y));
        h.z = f2bf(v.z); l.z = f2bf(v.z - bf2f(h.z));
        h.w = f2bf(v.w); l.w = f2bf(v.w - bf2f(h.w));
        ((ushort4*)xh)[i] = h;
        ((ushort4*)xl)[i] = l;
    }
}

// ---------------------------------------------------------------------------
// split_wt: W [d][n] fp32 -> Wt_hi/lo [n][d] bf16 (transposed), z selects Wq/Wk/Wv
// ---------------------------------------------------------------------------
__global__ __launch_bounds__(256) void split_wt(const float* __restrict__ Wq,
                                                const float* __restrict__ Wk,
                                                const float* __restrict__ Wv,
                                                unsigned short* __restrict__ Wsp) {
    const int z = blockIdx.z;
    const float* W = (z == 0) ? Wq : (z == 1) ? Wk : Wv;
    unsigned short* oh = Wsp + (size_t)z * 2 * WN;
    unsigned short* ol = oh + WN;

    __shared__ float t[64][65];
    const int d0 = blockIdx.x * 64, n0 = blockIdx.y * 64;
    const int tid = threadIdx.x;
    #pragma unroll
    for (int c = 0; c < 16; ++c) {
        int f = c * 256 + tid; int r = f >> 6, cc = f & 63;
        t[r][cc] = W[(size_t)(d0 + r) * DM + n0 + cc];
    }
    __syncthreads();
    #pragma unroll
    for (int c = 0; c < 16; ++c) {
        int f = c * 256 + tid; int r = f >> 6, cc = f & 63;
        float v = t[cc][r];                       // Wt[n0+r][d0+cc] = W[d0+cc][n0+r]
        unsigned short h = f2bf(v);
        size_t o = (size_t)(n0 + r) * DM + d0 + cc;
        oh[o] = h;
        ol[o] = f2bf(v - bf2f(h));
    }
}

// ---------------------------------------------------------------------------
// qk_mfma: C = x @ W (3-term split), writes C split into hi/lo bf16.
// grid (64, 8, 2): z=0 -> Q (into d_out), z=1 -> K.
// ---------------------------------------------------------------------------
__global__ __launch_bounds__(256, 2) void qk_mfma(
    const unsigned short* __restrict__ xh, const unsigned short* __restrict__ xl,
    const unsigned short* __restrict__ Wsp,
    unsigned short* __restrict__ Qh, unsigned short* __restrict__ Ql,
    unsigned short* __restrict__ Kh, unsigned short* __restrict__ Kl) {
    const int z = blockIdx.z;
    const unsigned short* Wh = Wsp + (size_t)z * 2 * WN;
    const unsigned short* Wl = Wh + WN;
    unsigned short* Ch = z ? Kh : Qh;
    unsigned short* Cl = z ? Kl : Ql;

    const int m0 = blockIdx.x * 128, n0 = blockIdx.y * 128;
    __shared__ short Ah[128 * 64], Al[128 * 64], Bh[128 * 64], Bl[128 * 64];
    const int tid = threadIdx.x, lane = tid & 63, w = tid >> 6;
    const int wr = w >> 1, wc = w & 1;

    f32x4 acc[4][4];
    #pragma unroll
    for (int i = 0; i < 4; ++i)
        #pragma unroll
        for (int j = 0; j < 4; ++j) acc[i][j] = (f32x4){0.f, 0.f, 0.f, 0.f};

    for (int k0 = 0; k0 < DM; k0 += 64) {
        stage_tile(xh + (size_t)m0 * DM + k0, DM, Ah, tid);
        stage_tile(xl + (size_t)m0 * DM + k0, DM, Al, tid);
        stage_tile(Wh + (size_t)n0 * DM + k0, DM, Bh, tid);
        stage_tile(Wl + (size_t)n0 * DM + k0, DM, Bl, tid);
        __syncthreads();
        #pragma unroll
        for (int ks = 0; ks < 2; ++ks) {
            const int g = ks * 4 + (lane >> 4);
            s16x8 a_h[4], a_l[4], b_h[4], b_l[4];
            #pragma unroll
            for (int mi = 0; mi < 4; ++mi) {
                int r = wr * 64 + mi * 16 + (lane & 15);
                a_h[mi] = lds_frag(Ah, r, g);
                a_l[mi] = lds_frag(Al, r, g);
            }
            #pragma unroll
            for (int ni = 0; ni < 4; ++ni) {
                int r = wc * 64 + ni * 16 + (lane & 15);
                b_h[ni] = lds_frag(Bh, r, g);
                b_l[ni] = lds_frag(Bl, r, g);
            }
            #pragma unroll
            for (int mi = 0; mi < 4; ++mi)
                #pragma unroll
                for (int ni = 0; ni < 4; ++ni) {
                    acc[mi][ni] = MFMA(a_h[mi], b_h[ni], acc[mi][ni]);
                    acc[mi][ni] = MFMA(a_h[mi], b_l[ni], acc[mi][ni]);
                    acc[mi][ni] = MFMA(a_l[mi], b_h[ni], acc[mi][ni]);
                }
        }
        __syncthreads();
    }
    // epilogue: split C into hi/lo bf16.  D: col=lane&15, row=(lane>>4)*4+r
    #pragma unroll
    for (int mi = 0; mi < 4; ++mi)
        #pragma unroll
        for (int ni = 0; ni < 4; ++ni)
            #pragma unroll
            for (int r = 0; r < 4; ++r) {
                int row = m0 + wr * 64 + mi * 16 + (lane >> 4) * 4 + r;
                int col = n0 + wc * 64 + ni * 16 + (lane & 15);
                float v = acc[mi][ni][r];
                unsigned short h = f2bf(v);
                size_t o = (size_t)row * DM + col;
                Ch[o] = h;
                Cl[o] = f2bf(v - bf2f(h));
            }
}

// ---------------------------------------------------------------------------
// vt_mfma: Vt[n][m] = (x @ Wv)^T via GEMM A=Wt_v(hi), B=x(hi), 1-term.
// grid (8 n-tiles over 1024, 64 m-tiles over 8192)
// ---------------------------------------------------------------------------
__global__ __launch_bounds__(256, 2) void vt_mfma(
    const unsigned short* __restrict__ Wsp, const unsigned short* __restrict__ xh,
    unsigned short* __restrict__ Vt) {
    const unsigned short* Wvh = Wsp + 4 * WN;   // Wv hi
    const int m0 = blockIdx.x * 128;            // over n-dim (1024)
    const int n0 = blockIdx.y * 128;            // over seq (8192)
    __shared__ short Ah[128 * 64], Bh[128 * 64];
    const int tid = threadIdx.x, lane = tid & 63, w = tid >> 6;
    const int wr = w >> 1, wc = w & 1;

    f32x4 acc[4][4];
    #pragma unroll
    for (int i = 0; i < 4; ++i)
        #pragma unroll
        for (int j = 0; j < 4; ++j) acc[i][j] = (f32x4){0.f, 0.f, 0.f, 0.f};

    for (int k0 = 0; k0 < DM; k0 += 64) {
        stage_tile(Wvh + (size_t)m0 * DM + k0, DM, Ah, tid);
        stage_tile(xh + (size_t)n0 * DM + k0, DM, Bh, tid);
        __syncthreads();
        #pragma unroll
        for (int ks = 0; ks < 2; ++ks) {
            const int g = ks * 4 + (lane >> 4);
            s16x8 a_h[4], b_h[4];
            #pragma unroll
            for (int mi = 0; mi < 4; ++mi)
                a_h[mi] = lds_frag(Ah, wr * 64 + mi * 16 + (lane & 15), g);
            #pragma unroll
            for (int ni = 0; ni < 4; ++ni)
                b_h[ni] = lds_frag(Bh, wc * 64 + ni * 16 + (lane & 15), g);
            #pragma unroll
            for (int mi = 0; mi < 4; ++mi)
                #pragma unroll
                for (int ni = 0; ni < 4; ++ni)
                    acc[mi][ni] = MFMA(a_h[mi], b_h[ni], acc[mi][ni]);
        }
        __syncthreads();
    }
    #pragma unroll
    for (int mi = 0; mi < 4; ++mi)
        #pragma unroll
        for (int ni = 0; ni < 4; ++ni)
            #pragma unroll
            for (int r = 0; r < 4; ++r) {
                int row = m0 + wr * 64 + mi * 16 + (lane >> 4) * 4 + r;
                int col = n0 + wc * 64 + ni * 16 + (lane & 15);
                Vt[(size_t)row * NTOK + col] = f2bf(acc[mi][ni][r]);
            }
}

// ---------------------------------------------------------------------------
// scores_mfma: P = mask(Q.K^T)/32, fp32 out.  3-term split.
// grid (16 jt, 16 t, 4 b), early-exit jt > t+1.
// ---------------------------------------------------------------------------
__global__ __launch_bounds__(256, 2) void scores_mfma(
    const unsigned short* __restrict__ Qh, const unsigned short* __restrict__ Ql,
    const unsigned short* __restrict__ Kh, const unsigned short* __restrict__ Kl,
    float* __restrict__ P) {
    const int jt = blockIdx.x, t = blockIdx.y, b = blockIdx.z;
    if (jt > t + 1) return;
    const int m0 = t * 128, n0 = jt * 128;
    const size_t qrow0 = (size_t)b * SEQ + m0;
    const size_t krow0 = (size_t)b * SEQ + n0;

    __shared__ short Ah[128 * 64], Al[128 * 64], Bh[128 * 64], Bl[128 * 64];
    const int tid = threadIdx.x, lane = tid & 63, w = tid >> 6;
    const int wr = w >> 1, wc = w & 1;

    f32x4 acc[4][4];
    #pragma unroll
    for (int i = 0; i < 4; ++i)
        #pragma unroll
        for (int j = 0; j < 4; ++j) acc[i][j] = (f32x4){0.f, 0.f, 0.f, 0.f};

    for (int k0 = 0; k0 < DM; k0 += 64) {
        stage_tile(Qh + qrow0 * DM + k0, DM, Ah, tid);
        stage_tile(Ql + qrow0 * DM + k0, DM, Al, tid);
        stage_tile(Kh + krow0 * DM + k0, DM, Bh, tid);
        stage_tile(Kl + krow0 * DM + k0, DM, Bl, tid);
        __syncthreads();
        #pragma unroll
        for (int ks = 0; ks < 2; ++ks) {
            const int g = ks * 4 + (lane >> 4);
            s16x8 a_h[4], a_l[4], b_h[4], b_l[4];
            #pragma unroll
            for (int mi = 0; mi < 4; ++mi) {
                int r = wr * 64 + mi * 16 + (lane & 15);
                a_h[mi] = lds_frag(Ah, r, g);
                a_l[mi] = lds_frag(Al, r, g);
            }
            #pragma unroll
            for (int ni = 0; ni < 4; ++ni) {
                int r = wc * 64 + ni * 16 + (lane & 15);
                b_h[ni] = lds_frag(Bh, r, g);
                b_l[ni] = lds_frag(Bl, r, g);
            }
            #pragma unroll
            for (int mi = 0; mi < 4; ++mi)
                #pragma unroll
                for (int ni = 0; ni < 4; ++ni) {
                    acc[mi][ni] = MFMA(a_h[mi], b_h[ni], acc[mi][ni]);
                    acc[mi][ni] = MFMA(a_h[mi], b_l[ni], acc[mi][ni]);
                    acc[mi][ni] = MFMA(a_l[mi], b_h[ni], acc[mi][ni]);
                }
        }
        __syncthreads();
    }
    const float scale = 1.0f / 32.0f;
    #pragma unroll
    for (int mi = 0; mi < 4; ++mi)
        #pragma unroll
        for (int ni = 0; ni < 4; ++ni)
            #pragma unroll
            for (int r = 0; r < 4; ++r) {
                int i = m0 + wr * 64 + mi * 16 + (lane >> 4) * 4 + r;  // within batch
                int j = n0 + wc * 64 + ni * 16 + (lane & 15);
                float v = (j <= i + 1) ? acc[mi][ni][r] * scale : -INFINITY;
                P[((size_t)b * SEQ + i) * SEQ + j] = v;
            }
}

// ---------------------------------------------------------------------------
// softmax_bf16: single-pass row softmax, fp32 logits in -> normalized bf16 out.
// One block (256 thr) per row; 8 statically-indexed f32 regs per thread.
// grid 8192.
// ---------------------------------------------------------------------------
__global__ __launch_bounds__(256) void softmax_bf16(
    const float* __restrict__ P, unsigned short* __restrict__ P2) {
    const int row = blockIdx.x;
    const int b = row >> 11, i = row & (SEQ - 1);
    const int t = i >> 7;
    const int L = min(SEQ, (t + 2) * 128);
    const float* p = P + ((size_t)b * SEQ + i) * SEQ;
    unsigned short* q = P2 + ((size_t)b * SEQ + i) * SEQ;
    const int tid = threadIdx.x;
    __shared__ float red[4];

    float v[8];
    #pragma unroll
    for (int c = 0; c < 8; ++c) {
        int j = c * 256 + tid;
        v[c] = (j < L) ? p[j] : -INFINITY;
    }
    float m = -INFINITY;
    #pragma unroll
    for (int c = 0; c < 8; ++c) m = fmaxf(m, v[c]);
    #pragma unroll
    for (int o = 32; o > 0; o >>= 1) m = fmaxf(m, __shfl_xor(m, o));
    if ((tid & 63) == 0) red[tid >> 6] = m;
    __syncthreads();
    m = fmaxf(fmaxf(red[0], red[1]), fmaxf(red[2], red[3]));
    __syncthreads();

    float s = 0.f;
    #pragma unroll
    for (int c = 0; c < 8; ++c) { v[c] = __expf(v[c] - m); s += v[c]; }
    #pragma unroll
    for (int o = 32; o > 0; o >>= 1) s += __shfl_xor(s, o);
    if ((tid & 63) == 0) red[tid >> 6] = s;
    __syncthreads();
    s = red[0] + red[1] + red[2] + red[3];
    const float inv = 1.f / s;

    #pragma unroll
    for (int c = 0; c < 8; ++c) {
        int j = c * 256 + tid;
        if (j < L) q[j] = f2bf(v[c] * inv);
    }
}

// ---------------------------------------------------------------------------
// pv_mfma: Out = P2(bf16) @ V.  Both tiles async-staged via global_load_lds.
// grid (8 n-tiles, 16 t, 4 b)
// ---------------------------------------------------------------------------
__global__ __launch_bounds__(256, 2) void pv_mfma(
    const unsigned short* __restrict__ P2, const unsigned short* __restrict__ Vt,
    float* __restrict__ Out) {
    const int bx = blockIdx.x, t = blockIdx.y, b = blockIdx.z;
    const int m0 = t * 128, n0 = bx * 128;
    const int jlim = min(SEQ, (t + 2) * 128);

    __shared__ short Pa[128 * 64], Vb[128 * 64];
    const int tid = threadIdx.x, lane = tid & 63, w = tid >> 6;
    const int wr = w >> 1, wc = w & 1;

    f32x4 acc[4][4];
    #pragma unroll
    for (int i = 0; i < 4; ++i)
        #pragma unroll
        for (int j = 0; j < 4; ++j) acc[i][j] = (f32x4){0.f, 0.f, 0.f, 0.f};

    for (int k0 = 0; k0 < jlim; k0 += 64) {
        stage_tile(P2 + ((size_t)b * SEQ + m0) * SEQ + k0, SEQ, Pa, tid);
        stage_tile(Vt + (size_t)n0 * NTOK + (size_t)b * SEQ + k0, NTOK, Vb, tid);
        __syncthreads();
        #pragma unroll
        for (int ks = 0; ks < 2; ++ks) {
            const int g = ks * 4 + (lane >> 4);
            s16x8 a_h[4], b_h[4];
            #pragma unroll
            for (int mi = 0; mi < 4; ++mi)
                a_h[mi] = lds_frag(Pa, wr * 64 + mi * 16 + (lane & 15), g);
            #pragma unroll
            for (int ni = 0; ni < 4; ++ni)
                b_h[ni] = lds_frag(Vb, wc * 64 + ni * 16 + (lane & 15), g);
            #pragma unroll
            for (int mi = 0; mi < 4; ++mi)
                #pragma unroll
                for (int ni = 0; ni < 4; ++ni)
                    acc[mi][ni] = MFMA(a_h[mi], b_h[ni], acc[mi][ni]);
        }
        __syncthreads();
    }
    #pragma unroll
    for (int mi = 0; mi < 4; ++mi)
        #pragma unroll
        for (int ni = 0; ni < 4; ++ni)
            #pragma unroll
            for (int r = 0; r < 4; ++r) {
                int i = m0 + wr * 64 + mi * 16 + (lane >> 4) * 4 + r;
                int col = n0 + wc * 64 + ni * 16 + (lane & 15);
                Out[((size_t)b * SEQ + i) * DM + col] = acc[mi][ni][r];
            }
}

// ---------------------------------------------------------------------------
extern "C" void kernel_launch(void* const* d_in, const int* in_sizes, int n_in,
                              void* d_out, int out_size, void* d_ws, size_t ws_size,
                              hipStream_t stream) {
    const float* x  = (const float*)d_in[0];
    const float* Wq = (const float*)d_in[1];
    const float* Wk = (const float*)d_in[2];
    const float* Wv = (const float*)d_in[3];

    // Workspace layout (bytes, NE = 8.39M elems):
    //   [0   , 4NE)  : Kh, Kl bf16 (live until scores)  -> reused as P2 bf16
    //   [4NE , 6NE)  : Vt bf16 [n=1024][m=8192]
    //   [6NE , 14NE) : P fp32 (scores); xh/xl/Wsp live inside before scores
    char* ws = (char*)d_ws;
    unsigned short* Kh = (unsigned short*)ws;            // NE elems
    unsigned short* Kl = Kh + NE;                        // NE elems
    unsigned short* Vt = Kl + NE;                        // NE elems
    float* P = (float*)(ws + 6 * NE);                    // 8*NE bytes
    unsigned short* P2 = (unsigned short*)ws;            // 2*NE elems, over Kh/Kl
    // x / W splits live INSIDE P's byte range (dead before scores writes P):
    unsigned short* xh  = (unsigned short*)(ws + 6 * NE);   // NE
    unsigned short* xl  = xh + NE;                          // NE
    unsigned short* Wsp = (unsigned short*)(ws + 10 * NE);  // 6*WN = 1.5*NE
    // Q splits use d_out as scratch (dead after scores; overwritten by Out):
    unsigned short* Qh = (unsigned short*)d_out;
    unsigned short* Ql = Qh + NE;

    split_x<<<2048, 256, 0, stream>>>(x, xh, xl);
    {
        dim3 g(16, 16, 3);
        split_wt<<<g, 256, 0, stream>>>(Wq, Wk, Wv, Wsp);
    }
    {
        dim3 g(NTOK / 128, DM / 128, 2);
        qk_mfma<<<g, 256, 0, stream>>>(xh, xl, Wsp, Qh, Ql, Kh, Kl);
    }
    {
        dim3 g(DM / 128, NTOK / 128, 1);
        vt_mfma<<<g, 256, 0, stream>>>(Wsp, xh, Vt);
    }
    {
        dim3 g(16, 16, 4);
        scores_mfma<<<g, 256, 0, stream>>>(Qh, Ql, Kh, Kl, P);
    }
    softmax_bf16<<<BATCH * SEQ, 256, 0, stream>>>(P, P2);
    {
        dim3 g(DM / 128, 16, 4);
        pv_mfma<<<g, 256, 0, stream>>>(P2, Vt, (float*)d_out);
    }
}